// Round 11
// baseline (245.878 us; speedup 1.0000x reference)
//
#include <hip/hip_runtime.h>

#define NODES 100000
#define EDGES 1600000
#define NB1 196          // col buckets: ceil(100000/512)
#define CAPB 10240       // per-bucket edge capacity (mean 8192)

typedef __attribute__((ext_vector_type(8))) short short8;
typedef __attribute__((ext_vector_type(4))) float f32x4;

// ---- bf16 helpers (RNE) -----------------------------------------------------
__device__ __forceinline__ unsigned short f2bf(float f) {
  unsigned int u = __float_as_uint(f);
  return (unsigned short)((u + 0x7fffu + ((u >> 16) & 1u)) >> 16);
}
__device__ __forceinline__ float2 up2(unsigned int u) {
  float2 f;
  f.x = __uint_as_float(u << 16);
  f.y = __uint_as_float(u & 0xffff0000u);
  return f;
}
__device__ __forceinline__ unsigned int pk2(float x, float y) {
  return ((unsigned int)f2bf(x)) | (((unsigned int)f2bf(y)) << 16);
}

// ---- pre: wconv (96 blocks) + bcur zero (1 block) ---------------------------
__global__ __launch_bounds__(256) void k_pre(const float* __restrict__ W1,
                                             const float* __restrict__ W2,
                                             unsigned short* __restrict__ Wb1,
                                             unsigned short* __restrict__ Wb2,
                                             int* __restrict__ bcur) {
  int bb = blockIdx.x;
  if (bb < 64) {
    int i = bb * 256 + threadIdx.x;        // 0..16383
    int n = i >> 7, k = i & 127;
    Wb1[i] = f2bf(W1[k * 128 + n]);
  } else if (bb < 96) {
    int i = (bb - 64) * 256 + threadIdx.x; // 0..8191
    int n = i >> 7, k = i & 127;
    Wb2[i] = f2bf(W2[k * 64 + n]);
  } else {
    if (threadIdx.x < NB1) bcur[threadIdx.x] = 0;
  }
}

// ---- S1: bin edges by col>>9; packed (row<<9)|col&511 into bucket regions ---
__global__ __launch_bounds__(256) void kS1(const int* __restrict__ rowi,
                                           const int* __restrict__ coli,
                                           int* __restrict__ bcur,
                                           unsigned int* __restrict__ binpk) {
  __shared__ int hist[NB1];
  __shared__ int base[NB1];
  const int t = threadIdx.x;
  const long long blk0 = (long long)blockIdx.x * 4096;
  for (int i = t; i < NB1; i += 256) hist[i] = 0;
  __syncthreads();
  int b[16];
  unsigned int pk[16];
#pragma unroll
  for (int q = 0; q < 4; ++q) {
    long long e = blk0 + q * 1024 + t * 4;
    if (e < EDGES) {
      int4 rv = *(const int4*)(rowi + e);
      int4 cv = *(const int4*)(coli + e);
      int rr[4] = {rv.x, rv.y, rv.z, rv.w};
      int cc[4] = {cv.x, cv.y, cv.z, cv.w};
#pragma unroll
      for (int i = 0; i < 4; ++i) {
        int idx = q * 4 + i;
        b[idx] = cc[i] >> 9;
        pk[idx] = ((unsigned int)rr[i] << 9) | (unsigned int)(cc[i] & 511);
        atomicAdd(&hist[b[idx]], 1);
      }
    } else {
#pragma unroll
      for (int i = 0; i < 4; ++i) b[q * 4 + i] = -1;
    }
  }
  __syncthreads();
  for (int i = t; i < NB1; i += 256)
    base[i] = hist[i] ? atomicAdd(&bcur[i], hist[i]) : 0;
  __syncthreads();
#pragma unroll
  for (int i = 0; i < 16; ++i) {
    if (b[i] >= 0) {
      int rel = atomicAdd(&base[b[i]], 1);
      if (rel < CAPB) binpk[b[i] * CAPB + rel] = pk[i];
    }
  }
}

// ---- S2a: per-bucket hist + scan -> offs/cnt/dinv (no scatter) --------------
__global__ __launch_bounds__(256) void kS2a(const unsigned int* __restrict__ binpk,
                                            const int* __restrict__ bcur,
                                            int* __restrict__ offs,
                                            int* __restrict__ cnt,
                                            float* __restrict__ dinv) {
  __shared__ int h[512];
  __shared__ int sc[256];
  const int k = blockIdx.x, t = threadIdx.x;
  const int beg = k * CAPB;
  const int c0 = k << 9;
  int n = bcur[k];
  if (n > CAPB) n = CAPB;
  h[t] = 0; h[t + 256] = 0;
  __syncthreads();
  for (int i = t; i < n; i += 256) atomicAdd(&h[binpk[beg + i] & 511u], 1);
  __syncthreads();
  int s0 = h[2 * t], s1 = h[2 * t + 1];
  sc[t] = s0 + s1;
  __syncthreads();
  for (int d = 1; d < 256; d <<= 1) {
    int v = (t >= d) ? sc[t - d] : 0;
    __syncthreads();
    sc[t] += v;
    __syncthreads();
  }
  int base2 = t ? sc[t - 1] : 0;
  int c = c0 + 2 * t;
  if (c < NODES) {
    offs[c] = beg + base2; cnt[c] = s0; dinv[c] = rsqrtf((float)(s0 + 1));
  }
  if (c + 1 < NODES) {
    offs[c + 1] = beg + base2 + s0; cnt[c + 1] = s1; dinv[c + 1] = rsqrtf((float)(s1 + 1));
  }
}

// ---- merged dispatch: blocks 0..195 = S2b scatter; 196..977 = gemm1 ---------
// gemm1: hdA/hdB[bf16 N][64] = halves of bf16( (X*dinv_row) @ W1 )
__global__ __launch_bounds__(256) void kS2bG1(const unsigned int* __restrict__ binpk,
                                              const int* __restrict__ bcur,
                                              const int* __restrict__ offs,
                                              int* __restrict__ srow,
                                              const float* __restrict__ X,
                                              const unsigned short* __restrict__ Wb,
                                              const float* __restrict__ dinv,
                                              unsigned short* __restrict__ hdA,
                                              unsigned short* __restrict__ hdB) {
  __shared__ __align__(16) unsigned short As[128 * 128];  // 32KB, both roles
  const int t = threadIdx.x;

  if (blockIdx.x < NB1) {
    // -------- S2b scatter role --------
    int* cur = (int*)As;  // [512]
    const int k = blockIdx.x;
    const int beg = k * CAPB;
    const int c0 = k << 9;
    int n = bcur[k];
    if (n > CAPB) n = CAPB;
    int c = c0 + t;
    cur[t] = (c < NODES) ? offs[c] : 0;
    c += 256;
    cur[t + 256] = (c < NODES) ? offs[c] : 0;
    __syncthreads();
    for (int i = t; i < n; i += 256) {
      unsigned int p = binpk[beg + i];
      int pos = atomicAdd(&cur[p & 511u], 1);
      srow[pos] = (int)(p >> 9);
    }
    return;
  }

  // -------- gemm1 role --------
  const int r0 = (blockIdx.x - NB1) * 128;
#pragma unroll
  for (int j = 0; j < 8; ++j) {
    int u = t + j * 256;
    int row = u >> 4, slot = u & 15;
    int gr = r0 + row;
    short8 v = {0, 0, 0, 0, 0, 0, 0, 0};
    if (gr < NODES) {
      float d = dinv[gr];
      const float4* px = (const float4*)(X + (long long)gr * 128 + slot * 8);
      float4 x0 = px[0], x1 = px[1];
      unsigned short tv[8];
      tv[0] = f2bf(x0.x * d); tv[1] = f2bf(x0.y * d);
      tv[2] = f2bf(x0.z * d); tv[3] = f2bf(x0.w * d);
      tv[4] = f2bf(x1.x * d); tv[5] = f2bf(x1.y * d);
      tv[6] = f2bf(x1.z * d); tv[7] = f2bf(x1.w * d);
      v = *(short8*)tv;
    }
    *(short8*)(&As[row * 128 + ((slot ^ (row & 7)) << 3)]) = v;
  }
  __syncthreads();

  const int wid = t >> 6, l = t & 63;
  const int wm = (wid >> 1) * 64, wn = (wid & 1) * 64;
  const int lr = l & 15, lk = l >> 4;
  f32x4 acc[4][4];
#pragma unroll
  for (int mi = 0; mi < 4; ++mi)
#pragma unroll
    for (int ni = 0; ni < 4; ++ni) acc[mi][ni] = (f32x4){0.f, 0.f, 0.f, 0.f};

#pragma unroll
  for (int ks = 0; ks < 4; ++ks) {
    int slot = ks * 4 + lk;
    short8 a[4], b[4];
#pragma unroll
    for (int mi = 0; mi < 4; ++mi) {
      int row = wm + mi * 16 + lr;
      a[mi] = *(short8*)(&As[row * 128 + ((slot ^ (row & 7)) << 3)]);
    }
#pragma unroll
    for (int ni = 0; ni < 4; ++ni) {
      int row = wn + ni * 16 + lr;
      b[ni] = *(const short8*)(Wb + row * 128 + slot * 8);
    }
#pragma unroll
    for (int mi = 0; mi < 4; ++mi)
#pragma unroll
      for (int ni = 0; ni < 4; ++ni)
        acc[mi][ni] = __builtin_amdgcn_mfma_f32_16x16x32_bf16(a[mi], b[ni], acc[mi][ni], 0, 0, 0);
  }
  __syncthreads();

  const int lr4 = lk * 4;
#pragma unroll
  for (int mi = 0; mi < 4; ++mi)
#pragma unroll
    for (int ni = 0; ni < 4; ++ni)
#pragma unroll
      for (int r = 0; r < 4; ++r)
        As[(wm + mi * 16 + lr4 + r) * 128 + wn + ni * 16 + lr] = f2bf(acc[mi][ni][r]);
  __syncthreads();
#pragma unroll
  for (int j = 0; j < 8; ++j) {
    int u = t + j * 256;
    int row = u >> 4, slot = u & 15;
    int gr = r0 + row;
    if (gr < NODES) {
      short8 v = *(short8*)(&As[row * 128 + slot * 8]);
      if (slot < 8)
        *(short8*)(hdA + (long long)gr * 64 + slot * 8) = v;
      else
        *(short8*)(hdB + (long long)gr * 64 + (slot - 8) * 8) = v;
    }
  }
}

// ---- agg1 half-pass: one node/wave, half-wave edge pairing, 64 features -----
// h1r[w][fb..fb+63] = bf16( relu( (gather+self)*dinv[w] + b1[fb..] ) * dinv[w] )
__global__ __launch_bounds__(256) void k_agg1h(const unsigned short* __restrict__ hdP,
                                               const int* __restrict__ srow,
                                               const int* __restrict__ offs,
                                               const int* __restrict__ cnt,
                                               const float* __restrict__ dinv,
                                               const float* __restrict__ b1,
                                               unsigned short* __restrict__ h1r,
                                               int fb) {
  int w = (blockIdx.x << 2) + (threadIdx.x >> 6);
  if (w >= NODES) return;
  const int lane = threadIdx.x & 63;
  const int f2 = lane & 31;   // feature-pair index within the 64-wide half
  const int eh = lane >> 5;   // edge half
  const unsigned int f4 = (unsigned int)f2 << 2;
  const char* H = (const char*)hdP;  // rows are 128B
  float2 a[4];
  if (eh == 0)
    a[0] = up2(*(const unsigned int*)(H + (((unsigned int)w) << 7) + f4));  // self-loop
  else
    a[0] = make_float2(0.f, 0.f);
#pragma unroll
  for (int q = 1; q < 4; ++q) a[q] = make_float2(0.f, 0.f);
  int off = offs[w], n = cnt[w];
  const int* sp = srow + off;
  int j = 0;
  for (; j + 8 <= n; j += 8) {
    unsigned int o[4];
#pragma unroll
    for (int q = 0; q < 4; ++q) o[q] = (((unsigned int)sp[j + 2 * q + eh]) << 7) + f4;
#pragma unroll
    for (int q = 0; q < 4; ++q) {
      float2 v = up2(*(const unsigned int*)(H + o[q]));
      a[q].x += v.x; a[q].y += v.y;
    }
  }
  for (; j + 2 <= n; j += 2) {
    float2 v = up2(*(const unsigned int*)(H + (((unsigned int)sp[j + eh]) << 7) + f4));
    a[0].x += v.x; a[0].y += v.y;
  }
  if (j < n && eh == 0) {
    float2 v = up2(*(const unsigned int*)(H + (((unsigned int)sp[j]) << 7) + f4));
    a[0].x += v.x; a[0].y += v.y;
  }
  float ax = (a[0].x + a[1].x) + (a[2].x + a[3].x);
  float ay = (a[0].y + a[1].y) + (a[2].y + a[3].y);
  ax += __shfl_xor(ax, 32);
  ay += __shfl_xor(ay, 32);
  if (eh == 0) {
    float dc = dinv[w];
    float2 b = ((const float2*)b1)[(fb >> 1) + f2];
    float ox = fmaxf(fmaf(ax, dc, b.x), 0.f) * dc;  // pre-scaled for layer-2
    float oy = fmaxf(fmaf(ay, dc, b.y), 0.f) * dc;
    ((unsigned int*)h1r)[(long long)w * 64 + (fb >> 1) + f2] = pk2(ox, oy);
  }
}

// ---- MFMA GEMM layer2: HD2[bf16] = bf16( h1r @ W2 ), B from global ----------
__global__ __launch_bounds__(256) void k_gemm2(const unsigned short* __restrict__ H1,
                                               const unsigned short* __restrict__ Wb,
                                               unsigned short* __restrict__ HD2,
                                               int nrows) {
  __shared__ unsigned short As[128 * 128];
  const int t = threadIdx.x;
  const int r0 = blockIdx.x * 128;

#pragma unroll
  for (int j = 0; j < 8; ++j) {
    int u = t + j * 256;
    int row = u >> 4, slot = u & 15;
    int gr = r0 + row;
    short8 v = {0, 0, 0, 0, 0, 0, 0, 0};
    if (gr < nrows) v = *(const short8*)(H1 + (long long)gr * 128 + slot * 8);
    *(short8*)(&As[row * 128 + ((slot ^ (row & 7)) << 3)]) = v;
  }
  __syncthreads();

  const int wid = t >> 6, l = t & 63;
  const int wm = wid * 32;
  const int lr = l & 15, lk = l >> 4;
  f32x4 acc[2][4];
#pragma unroll
  for (int mi = 0; mi < 2; ++mi)
#pragma unroll
    for (int ni = 0; ni < 4; ++ni) acc[mi][ni] = (f32x4){0.f, 0.f, 0.f, 0.f};

#pragma unroll
  for (int ks = 0; ks < 4; ++ks) {
    int slot = ks * 4 + lk;
    short8 a[2], b[4];
#pragma unroll
    for (int mi = 0; mi < 2; ++mi) {
      int row = wm + mi * 16 + lr;
      a[mi] = *(short8*)(&As[row * 128 + ((slot ^ (row & 7)) << 3)]);
    }
#pragma unroll
    for (int ni = 0; ni < 4; ++ni) {
      int row = ni * 16 + lr;
      b[ni] = *(const short8*)(Wb + row * 128 + slot * 8);
    }
#pragma unroll
    for (int mi = 0; mi < 2; ++mi)
#pragma unroll
      for (int ni = 0; ni < 4; ++ni)
        acc[mi][ni] = __builtin_amdgcn_mfma_f32_16x16x32_bf16(a[mi], b[ni], acc[mi][ni], 0, 0, 0);
  }
  __syncthreads();

  const int lr4 = lk * 4;
#pragma unroll
  for (int mi = 0; mi < 2; ++mi)
#pragma unroll
    for (int ni = 0; ni < 4; ++ni)
#pragma unroll
      for (int r = 0; r < 4; ++r)
        As[(wm + mi * 16 + lr4 + r) * 64 + ni * 16 + lr] = f2bf(acc[mi][ni][r]);
  __syncthreads();
#pragma unroll
  for (int j = 0; j < 4; ++j) {
    int u = t + j * 256;
    int row = u >> 3, slot = u & 7;
    int gr = r0 + row;
    if (gr < nrows)
      *(short8*)(HD2 + (long long)gr * 64 + slot * 8) = *(short8*)(&As[row * 64 + slot * 8]);
  }
}

// ---- CSR aggregation, F=64: half-wave pairing (2 edges/step, 1 line/edge) ---
__global__ __launch_bounds__(256) void k_agg2(const unsigned short* __restrict__ hd2,
                                              const int* __restrict__ srow,
                                              const int* __restrict__ offs,
                                              const int* __restrict__ cnt,
                                              const float* __restrict__ dinv,
                                              const float* __restrict__ b2,
                                              float* __restrict__ outp) {
  int w = (blockIdx.x << 2) + (threadIdx.x >> 6);
  if (w >= NODES) return;
  const int lane = threadIdx.x & 63;
  const int f2 = lane & 31;   // feature-pair index
  const int eh = lane >> 5;   // edge half
  const unsigned int f4 = (unsigned int)f2 << 2;
  const char* H = (const char*)hd2;  // rows are 128B
  float2 a[4];
  if (eh == 0)
    a[0] = up2(*(const unsigned int*)(H + (((unsigned int)w) << 7) + f4));  // self-loop
  else
    a[0] = make_float2(0.f, 0.f);
#pragma unroll
  for (int q = 1; q < 4; ++q) a[q] = make_float2(0.f, 0.f);
  int off = offs[w], n = cnt[w];
  const int* sp = srow + off;
  int j = 0;
  for (; j + 8 <= n; j += 8) {
    unsigned int o[4];
#pragma unroll
    for (int q = 0; q < 4; ++q) o[q] = (((unsigned int)sp[j + 2 * q + eh]) << 7) + f4;
#pragma unroll
    for (int q = 0; q < 4; ++q) {
      float2 v = up2(*(const unsigned int*)(H + o[q]));
      a[q].x += v.x; a[q].y += v.y;
    }
  }
  for (; j + 2 <= n; j += 2) {
    float2 v = up2(*(const unsigned int*)(H + (((unsigned int)sp[j + eh]) << 7) + f4));
    a[0].x += v.x; a[0].y += v.y;
  }
  if (j < n && eh == 0) {
    float2 v = up2(*(const unsigned int*)(H + (((unsigned int)sp[j]) << 7) + f4));
    a[0].x += v.x; a[0].y += v.y;
  }
  float ax = (a[0].x + a[1].x) + (a[2].x + a[3].x);
  float ay = (a[0].y + a[1].y) + (a[2].y + a[3].y);
  ax += __shfl_xor(ax, 32);
  ay += __shfl_xor(ay, 32);
  if (eh == 0) {
    float dc = dinv[w];
    float2 b = ((const float2*)b2)[f2];
    float2 o;
    o.x = fmaf(ax, dc, b.x);
    o.y = fmaf(ay, dc, b.y);
    ((float2*)outp)[(long long)w * 32 + f2] = o;
  }
}

extern "C" void kernel_launch(void* const* d_in, const int* in_sizes, int n_in,
                              void* d_out, int out_size, void* d_ws, size_t ws_size,
                              hipStream_t stream) {
  const float* x  = (const float*)d_in[0];
  const int*   ei = (const int*)d_in[1];  // [2, E]: row then col
  const float* W1 = (const float*)d_in[2];
  const float* b1 = (const float*)d_in[3];
  const float* W2 = (const float*)d_in[4];
  const float* b2 = (const float*)d_in[5];
  float* out = (float*)d_out;

  float* ws   = (float*)d_ws;
  float* dinv = ws;                          // 100352 f
  int*  cnt   = (int*)(ws + 100352);         // 100352 i
  int*  offs  = cnt + 100352;                // 100352 i
  int*  bcur  = offs + 100352;               // 256 i
  unsigned short* Wb1 = (unsigned short*)(bcur + 256);   // 128*128 bf16
  unsigned short* Wb2 = Wb1 + 128 * 128;                 // 64*128 bf16
  int*  srow  = (int*)(Wb2 + 64 * 128);      // NB1*CAPB i (8MB)
  unsigned int* binpk = (unsigned int*)(srow + NB1 * CAPB);     // NB1*CAPB u32
  unsigned short* hdA = (unsigned short*)(binpk + NB1 * CAPB);  // NODES*64 bf16
  unsigned short* hdB = hdA + (long long)NODES * 64;            // NODES*64 bf16
  unsigned short* h1r = hdB + (long long)NODES * 64;            // NODES*128 bf16
  unsigned short* hd2 = hdA;  // reuse hdA (dead after agg1 passes)

  const int* rowi = ei;
  const int* coli = ei + EDGES;

  // ---- build ----
  k_pre<<<dim3(97), dim3(256), 0, stream>>>(W1, W2, Wb1, Wb2, bcur);
  kS1<<<dim3((EDGES + 4095) / 4096), dim3(256), 0, stream>>>(rowi, coli, bcur, binpk);
  kS2a<<<dim3(NB1), dim3(256), 0, stream>>>(binpk, bcur, offs, cnt, dinv);
  kS2bG1<<<dim3(NB1 + 782), dim3(256), 0, stream>>>(binpk, bcur, offs, srow,
                                                    x, Wb1, dinv, hdA, hdB);

  // ---- layer 1 aggregation (two feature halves) ----
  k_agg1h<<<dim3((NODES + 3) / 4), dim3(256), 0, stream>>>(hdA, srow, offs, cnt, dinv, b1, h1r, 0);
  k_agg1h<<<dim3((NODES + 3) / 4), dim3(256), 0, stream>>>(hdB, srow, offs, cnt, dinv, b1, h1r, 64);

  // ---- layer 2 ----
  k_gemm2<<<dim3((NODES + 127) / 128), dim3(256), 0, stream>>>(h1r, Wb2, hd2, NODES);
  k_agg2<<<dim3((NODES + 3) / 4), dim3(256), 0, stream>>>(hd2, srow, offs, cnt, dinv, b2, out);
}

// Round 12
// 200.437 us; speedup vs baseline: 1.2267x; 1.2267x over previous
//
#include <hip/hip_runtime.h>

#define NODES 100000
#define EDGES 1600000
#define NB1 196          // col buckets: ceil(100000/512)
#define CAPB 10240       // per-bucket edge capacity (mean 8192)

typedef __attribute__((ext_vector_type(8))) short short8;
typedef __attribute__((ext_vector_type(4))) float f32x4;

// ---- bf16 helpers (RNE) -----------------------------------------------------
__device__ __forceinline__ unsigned short f2bf(float f) {
  unsigned int u = __float_as_uint(f);
  return (unsigned short)((u + 0x7fffu + ((u >> 16) & 1u)) >> 16);
}
__device__ __forceinline__ float2 up2(unsigned int u) {
  float2 f;
  f.x = __uint_as_float(u << 16);
  f.y = __uint_as_float(u & 0xffff0000u);
  return f;
}
__device__ __forceinline__ unsigned int pk2(float x, float y) {
  return ((unsigned int)f2bf(x)) | (((unsigned int)f2bf(y)) << 16);
}

// ---- S1 + weight conversion, one dispatch (R8 proven) -----------------------
__global__ __launch_bounds__(256) void kS1W(const int* __restrict__ rowi,
                                            const int* __restrict__ coli,
                                            int* __restrict__ bcur,
                                            unsigned int* __restrict__ binpk,
                                            const float* __restrict__ W1,
                                            const float* __restrict__ W2,
                                            unsigned short* __restrict__ Wb1,
                                            unsigned short* __restrict__ Wb2) {
  if (blockIdx.x >= 391) {
    int bb = blockIdx.x - 391;
    if (bb < 64) {
      int i = bb * 256 + threadIdx.x;        // 0..16383
      int n = i >> 7, k = i & 127;
      Wb1[i] = f2bf(W1[k * 128 + n]);
    } else {
      int i = (bb - 64) * 256 + threadIdx.x; // 0..8191
      int n = i >> 7, k = i & 127;
      Wb2[i] = f2bf(W2[k * 64 + n]);
    }
    return;
  }
  __shared__ int hist[NB1];
  __shared__ int base[NB1];
  const int t = threadIdx.x;
  const long long blk0 = (long long)blockIdx.x * 4096;
  for (int i = t; i < NB1; i += 256) hist[i] = 0;
  __syncthreads();
  int b[16];
  unsigned int pk[16];
#pragma unroll
  for (int q = 0; q < 4; ++q) {
    long long e = blk0 + q * 1024 + t * 4;
    if (e < EDGES) {
      int4 rv = *(const int4*)(rowi + e);
      int4 cv = *(const int4*)(coli + e);
      int rr[4] = {rv.x, rv.y, rv.z, rv.w};
      int cc[4] = {cv.x, cv.y, cv.z, cv.w};
#pragma unroll
      for (int i = 0; i < 4; ++i) {
        int idx = q * 4 + i;
        b[idx] = cc[i] >> 9;
        pk[idx] = ((unsigned int)rr[i] << 9) | (unsigned int)(cc[i] & 511);
        atomicAdd(&hist[b[idx]], 1);
      }
    } else {
#pragma unroll
      for (int i = 0; i < 4; ++i) b[q * 4 + i] = -1;
    }
  }
  __syncthreads();
  for (int i = t; i < NB1; i += 256)
    base[i] = hist[i] ? atomicAdd(&bcur[i], hist[i]) : 0;
  __syncthreads();
#pragma unroll
  for (int i = 0; i < 16; ++i) {
    if (b[i] >= 0) {
      int rel = atomicAdd(&base[b[i]], 1);
      if (rel < CAPB) binpk[b[i] * CAPB + rel] = pk[i];
    }
  }
}

// ---- S2: per-bucket hist + scan + LDS-cached sort; emits CSR + dinv ---------
__global__ __launch_bounds__(256) void kS2(const unsigned int* __restrict__ binpk,
                                           const int* __restrict__ bcur,
                                           int* __restrict__ srow,
                                           int* __restrict__ offs,
                                           int* __restrict__ cnt,
                                           float* __restrict__ dinv) {
  __shared__ int h[512];
  __shared__ int sc[256];
  __shared__ unsigned int cachepk[CAPB];
  const int k = blockIdx.x, t = threadIdx.x;
  const int beg = k * CAPB;
  const int c0 = k << 9;
  int n = bcur[k];
  if (n > CAPB) n = CAPB;
  h[t] = 0; h[t + 256] = 0;
  __syncthreads();
  for (int i = t; i < n; i += 256) {
    unsigned int p = binpk[beg + i];
    cachepk[i] = p;
    atomicAdd(&h[p & 511u], 1);
  }
  __syncthreads();
  int s0 = h[2 * t], s1 = h[2 * t + 1];
  sc[t] = s0 + s1;
  __syncthreads();
  for (int d = 1; d < 256; d <<= 1) {
    int v = (t >= d) ? sc[t - d] : 0;
    __syncthreads();
    sc[t] += v;
    __syncthreads();
  }
  int base2 = t ? sc[t - 1] : 0;
  int c = c0 + 2 * t;
  if (c < NODES) {
    offs[c] = beg + base2; cnt[c] = s0; dinv[c] = rsqrtf((float)(s0 + 1));
  }
  if (c + 1 < NODES) {
    offs[c + 1] = beg + base2 + s0; cnt[c + 1] = s1; dinv[c + 1] = rsqrtf((float)(s1 + 1));
  }
  __syncthreads();
  h[2 * t] = beg + base2;
  h[2 * t + 1] = beg + base2 + s0;
  __syncthreads();
  for (int i = t; i < n; i += 256) {
    unsigned int p = cachepk[i];
    int pos = atomicAdd(&h[p & 511u], 1);
    srow[pos] = (int)(p >> 9);
  }
}

// ---- MFMA GEMM layer1: HD[bf16] = bf16( (X*dinv_row) @ W1 ), B from global --
__global__ __launch_bounds__(256) void k_gemm1(const float* __restrict__ X,
                                               const unsigned short* __restrict__ Wb,
                                               const float* __restrict__ dinv,
                                               unsigned short* __restrict__ HD,
                                               int nrows) {
  __shared__ unsigned short As[128 * 128];
  const int t = threadIdx.x;
  const int r0 = blockIdx.x * 128;

#pragma unroll
  for (int j = 0; j < 8; ++j) {
    int u = t + j * 256;
    int row = u >> 4, slot = u & 15;
    int gr = r0 + row;
    short8 v = {0, 0, 0, 0, 0, 0, 0, 0};
    if (gr < nrows) {
      float d = dinv[gr];
      const float4* px = (const float4*)(X + (long long)gr * 128 + slot * 8);
      float4 x0 = px[0], x1 = px[1];
      unsigned short tv[8];
      tv[0] = f2bf(x0.x * d); tv[1] = f2bf(x0.y * d);
      tv[2] = f2bf(x0.z * d); tv[3] = f2bf(x0.w * d);
      tv[4] = f2bf(x1.x * d); tv[5] = f2bf(x1.y * d);
      tv[6] = f2bf(x1.z * d); tv[7] = f2bf(x1.w * d);
      v = *(short8*)tv;
    }
    *(short8*)(&As[row * 128 + ((slot ^ (row & 7)) << 3)]) = v;
  }
  __syncthreads();

  const int wid = t >> 6, l = t & 63;
  const int wm = (wid >> 1) * 64, wn = (wid & 1) * 64;
  const int lr = l & 15, lk = l >> 4;
  f32x4 acc[4][4];
#pragma unroll
  for (int mi = 0; mi < 4; ++mi)
#pragma unroll
    for (int ni = 0; ni < 4; ++ni) acc[mi][ni] = (f32x4){0.f, 0.f, 0.f, 0.f};

#pragma unroll
  for (int ks = 0; ks < 4; ++ks) {
    int slot = ks * 4 + lk;
    short8 a[4], b[4];
#pragma unroll
    for (int mi = 0; mi < 4; ++mi) {
      int row = wm + mi * 16 + lr;
      a[mi] = *(short8*)(&As[row * 128 + ((slot ^ (row & 7)) << 3)]);
    }
#pragma unroll
    for (int ni = 0; ni < 4; ++ni) {
      int row = wn + ni * 16 + lr;
      b[ni] = *(const short8*)(Wb + row * 128 + slot * 8);
    }
#pragma unroll
    for (int mi = 0; mi < 4; ++mi)
#pragma unroll
      for (int ni = 0; ni < 4; ++ni)
        acc[mi][ni] = __builtin_amdgcn_mfma_f32_16x16x32_bf16(a[mi], b[ni], acc[mi][ni], 0, 0, 0);
  }
  __syncthreads();

  const int lr4 = lk * 4;
#pragma unroll
  for (int mi = 0; mi < 4; ++mi)
#pragma unroll
    for (int ni = 0; ni < 4; ++ni)
#pragma unroll
      for (int r = 0; r < 4; ++r)
        As[(wm + mi * 16 + lr4 + r) * 128 + wn + ni * 16 + lr] = f2bf(acc[mi][ni][r]);
  __syncthreads();
#pragma unroll
  for (int j = 0; j < 8; ++j) {
    int u = t + j * 256;
    int row = u >> 4, slot = u & 15;
    int gr = r0 + row;
    if (gr < nrows)
      *(short8*)(HD + (long long)gr * 128 + slot * 8) = *(short8*)(&As[row * 128 + slot * 8]);
  }
}

// ---- CSR aggregation, F=128 bf16 in / bf16 out (R5/R7 proven form) ----------
__global__ __launch_bounds__(256) void k_agg1(const unsigned short* __restrict__ hd,
                                              const int* __restrict__ srow,
                                              const int* __restrict__ offs,
                                              const int* __restrict__ cnt,
                                              const float* __restrict__ dinv,
                                              const float* __restrict__ b1,
                                              unsigned short* __restrict__ h1r) {
  int w = (blockIdx.x << 2) + (threadIdx.x >> 6);
  if (w >= NODES) return;
  int lane = threadIdx.x & 63;
  const unsigned int* H = (const unsigned int*)hd;
  float2 a0 = up2(H[(long long)w * 64 + lane]);  // self-loop
  float2 a1 = {0.f, 0.f}, a2 = {0.f, 0.f}, a3 = {0.f, 0.f};
  float2 a4 = {0.f, 0.f}, a5 = {0.f, 0.f}, a6 = {0.f, 0.f}, a7 = {0.f, 0.f};
  int off = offs[w], n = cnt[w];
  int j = 0;
  for (; j + 7 < n; j += 8) {
    int r0 = srow[off + j],     r1 = srow[off + j + 1];
    int r2 = srow[off + j + 2], r3 = srow[off + j + 3];
    int r4 = srow[off + j + 4], r5 = srow[off + j + 5];
    int r6 = srow[off + j + 6], r7 = srow[off + j + 7];
    float2 v0 = up2(H[(long long)r0 * 64 + lane]);
    float2 v1 = up2(H[(long long)r1 * 64 + lane]);
    float2 v2 = up2(H[(long long)r2 * 64 + lane]);
    float2 v3 = up2(H[(long long)r3 * 64 + lane]);
    float2 v4 = up2(H[(long long)r4 * 64 + lane]);
    float2 v5 = up2(H[(long long)r5 * 64 + lane]);
    float2 v6 = up2(H[(long long)r6 * 64 + lane]);
    float2 v7 = up2(H[(long long)r7 * 64 + lane]);
    a0.x += v0.x; a0.y += v0.y; a1.x += v1.x; a1.y += v1.y;
    a2.x += v2.x; a2.y += v2.y; a3.x += v3.x; a3.y += v3.y;
    a4.x += v4.x; a4.y += v4.y; a5.x += v5.x; a5.y += v5.y;
    a6.x += v6.x; a6.y += v6.y; a7.x += v7.x; a7.y += v7.y;
  }
  for (; j + 3 < n; j += 4) {
    int r0 = srow[off + j],     r1 = srow[off + j + 1];
    int r2 = srow[off + j + 2], r3 = srow[off + j + 3];
    float2 v0 = up2(H[(long long)r0 * 64 + lane]);
    float2 v1 = up2(H[(long long)r1 * 64 + lane]);
    float2 v2 = up2(H[(long long)r2 * 64 + lane]);
    float2 v3 = up2(H[(long long)r3 * 64 + lane]);
    a0.x += v0.x; a0.y += v0.y; a1.x += v1.x; a1.y += v1.y;
    a2.x += v2.x; a2.y += v2.y; a3.x += v3.x; a3.y += v3.y;
  }
  for (; j < n; ++j) {
    float2 v = up2(H[(long long)srow[off + j] * 64 + lane]);
    a0.x += v.x; a0.y += v.y;
  }
  float ax = ((a0.x + a1.x) + (a2.x + a3.x)) + ((a4.x + a5.x) + (a6.x + a7.x));
  float ay = ((a0.y + a1.y) + (a2.y + a3.y)) + ((a4.y + a5.y) + (a6.y + a7.y));
  float dc = dinv[w];
  float2 b = ((const float2*)b1)[lane];
  float ox = fmaxf(fmaf(ax, dc, b.x), 0.f) * dc;  // pre-scaled for layer-2
  float oy = fmaxf(fmaf(ay, dc, b.y), 0.f) * dc;
  ((unsigned int*)h1r)[(long long)w * 64 + lane] = pk2(ox, oy);
}

// ---- MFMA GEMM layer2: HD2[bf16] = bf16( h1r @ W2 ), B from global ----------
__global__ __launch_bounds__(256) void k_gemm2(const unsigned short* __restrict__ H1,
                                               const unsigned short* __restrict__ Wb,
                                               unsigned short* __restrict__ HD2,
                                               int nrows) {
  __shared__ unsigned short As[128 * 128];
  const int t = threadIdx.x;
  const int r0 = blockIdx.x * 128;

#pragma unroll
  for (int j = 0; j < 8; ++j) {
    int u = t + j * 256;
    int row = u >> 4, slot = u & 15;
    int gr = r0 + row;
    short8 v = {0, 0, 0, 0, 0, 0, 0, 0};
    if (gr < nrows) v = *(const short8*)(H1 + (long long)gr * 128 + slot * 8);
    *(short8*)(&As[row * 128 + ((slot ^ (row & 7)) << 3)]) = v;
  }
  __syncthreads();

  const int wid = t >> 6, l = t & 63;
  const int wm = wid * 32;
  const int lr = l & 15, lk = l >> 4;
  f32x4 acc[2][4];
#pragma unroll
  for (int mi = 0; mi < 2; ++mi)
#pragma unroll
    for (int ni = 0; ni < 4; ++ni) acc[mi][ni] = (f32x4){0.f, 0.f, 0.f, 0.f};

#pragma unroll
  for (int ks = 0; ks < 4; ++ks) {
    int slot = ks * 4 + lk;
    short8 a[2], b[4];
#pragma unroll
    for (int mi = 0; mi < 2; ++mi) {
      int row = wm + mi * 16 + lr;
      a[mi] = *(short8*)(&As[row * 128 + ((slot ^ (row & 7)) << 3)]);
    }
#pragma unroll
    for (int ni = 0; ni < 4; ++ni) {
      int row = ni * 16 + lr;
      b[ni] = *(const short8*)(Wb + row * 128 + slot * 8);
    }
#pragma unroll
    for (int mi = 0; mi < 2; ++mi)
#pragma unroll
      for (int ni = 0; ni < 4; ++ni)
        acc[mi][ni] = __builtin_amdgcn_mfma_f32_16x16x32_bf16(a[mi], b[ni], acc[mi][ni], 0, 0, 0);
  }
  __syncthreads();

  const int lr4 = lk * 4;
#pragma unroll
  for (int mi = 0; mi < 2; ++mi)
#pragma unroll
    for (int ni = 0; ni < 4; ++ni)
#pragma unroll
      for (int r = 0; r < 4; ++r)
        As[(wm + mi * 16 + lr4 + r) * 64 + ni * 16 + lr] = f2bf(acc[mi][ni][r]);
  __syncthreads();
#pragma unroll
  for (int j = 0; j < 4; ++j) {
    int u = t + j * 256;
    int row = u >> 3, slot = u & 7;
    int gr = r0 + row;
    if (gr < nrows)
      *(short8*)(HD2 + (long long)gr * 64 + slot * 8) = *(short8*)(&As[row * 64 + slot * 8]);
  }
}

// ---- CSR aggregation, F=64: QUARTER-wave (16 lanes/edge, 16 edges/step) -----
// Each quarter reads a full 128B row (uint2/lane = 4 features). 4 positions
// x 4 quarters = 16 lines in flight per wave (matches agg1's proven MLP).
__global__ __launch_bounds__(256) void k_agg2(const unsigned short* __restrict__ hd2,
                                              const int* __restrict__ srow,
                                              const int* __restrict__ offs,
                                              const int* __restrict__ cnt,
                                              const float* __restrict__ dinv,
                                              const float* __restrict__ b2,
                                              float* __restrict__ outp) {
  int w = (blockIdx.x << 2) + (threadIdx.x >> 6);
  if (w >= NODES) return;
  const int lane = threadIdx.x & 63;
  const int fq = lane & 15;   // feature quad: features 4fq..4fq+3
  const int eq = lane >> 4;   // edge quarter 0..3
  const unsigned int f8 = (unsigned int)fq << 3;  // byte offset of uint2
  const char* H = (const char*)hd2;  // rows are 128B

  float4 a0 = {0.f, 0.f, 0.f, 0.f}, a1 = a0, a2 = a0, a3 = a0;
  if (eq == 0) {  // self-loop
    uint2 u = *(const uint2*)(H + (((unsigned int)w) << 7) + f8);
    float2 lo = up2(u.x), hi = up2(u.y);
    a0.x = lo.x; a0.y = lo.y; a0.z = hi.x; a0.w = hi.y;
  }
  int off = offs[w], n = cnt[w];
  const int* sp = srow + off;
  int j = 0;
  for (; j + 16 <= n; j += 16) {
    unsigned int o0 = (((unsigned int)sp[j + eq])      << 7) + f8;
    unsigned int o1 = (((unsigned int)sp[j + 4 + eq])  << 7) + f8;
    unsigned int o2 = (((unsigned int)sp[j + 8 + eq])  << 7) + f8;
    unsigned int o3 = (((unsigned int)sp[j + 12 + eq]) << 7) + f8;
    uint2 u0 = *(const uint2*)(H + o0);
    uint2 u1 = *(const uint2*)(H + o1);
    uint2 u2 = *(const uint2*)(H + o2);
    uint2 u3 = *(const uint2*)(H + o3);
    float2 l0 = up2(u0.x), h0 = up2(u0.y);
    float2 l1 = up2(u1.x), h1 = up2(u1.y);
    float2 l2 = up2(u2.x), h2 = up2(u2.y);
    float2 l3 = up2(u3.x), h3 = up2(u3.y);
    a0.x += l0.x; a0.y += l0.y; a0.z += h0.x; a0.w += h0.y;
    a1.x += l1.x; a1.y += l1.y; a1.z += h1.x; a1.w += h1.y;
    a2.x += l2.x; a2.y += l2.y; a2.z += h2.x; a2.w += h2.y;
    a3.x += l3.x; a3.y += l3.y; a3.z += h3.x; a3.w += h3.y;
  }
  // tail: rem in [0,15], all quads issued independently (parallel loads)
  int rem = n - j;
  if (rem >= 4) {
    uint2 u = *(const uint2*)(H + ((((unsigned int)sp[j + eq]) << 7) + f8));
    float2 lo = up2(u.x), hi = up2(u.y);
    a0.x += lo.x; a0.y += lo.y; a0.z += hi.x; a0.w += hi.y;
  }
  if (rem >= 8) {
    uint2 u = *(const uint2*)(H + ((((unsigned int)sp[j + 4 + eq]) << 7) + f8));
    float2 lo = up2(u.x), hi = up2(u.y);
    a1.x += lo.x; a1.y += lo.y; a1.z += hi.x; a1.w += hi.y;
  }
  if (rem >= 12) {
    uint2 u = *(const uint2*)(H + ((((unsigned int)sp[j + 8 + eq]) << 7) + f8));
    float2 lo = up2(u.x), hi = up2(u.y);
    a2.x += lo.x; a2.y += lo.y; a2.z += hi.x; a2.w += hi.y;
  }
  int last = j + (rem & ~3);
  if (eq < (rem & 3)) {
    uint2 u = *(const uint2*)(H + ((((unsigned int)sp[last + eq]) << 7) + f8));
    float2 lo = up2(u.x), hi = up2(u.y);
    a3.x += lo.x; a3.y += lo.y; a3.z += hi.x; a3.w += hi.y;
  }
  float4 s;
  s.x = (a0.x + a1.x) + (a2.x + a3.x);
  s.y = (a0.y + a1.y) + (a2.y + a3.y);
  s.z = (a0.z + a1.z) + (a2.z + a3.z);
  s.w = (a0.w + a1.w) + (a2.w + a3.w);
  // reduce across edge quarters (lane xor 16, then 32)
  s.x += __shfl_xor(s.x, 16); s.y += __shfl_xor(s.y, 16);
  s.z += __shfl_xor(s.z, 16); s.w += __shfl_xor(s.w, 16);
  s.x += __shfl_xor(s.x, 32); s.y += __shfl_xor(s.y, 32);
  s.z += __shfl_xor(s.z, 32); s.w += __shfl_xor(s.w, 32);
  if (eq == 0) {
    float dc = dinv[w];
    float4 b = ((const float4*)b2)[fq];
    float4 o;
    o.x = fmaf(s.x, dc, b.x);
    o.y = fmaf(s.y, dc, b.y);
    o.z = fmaf(s.z, dc, b.z);
    o.w = fmaf(s.w, dc, b.w);
    ((float4*)outp)[(long long)w * 16 + fq] = o;
  }
}

extern "C" void kernel_launch(void* const* d_in, const int* in_sizes, int n_in,
                              void* d_out, int out_size, void* d_ws, size_t ws_size,
                              hipStream_t stream) {
  const float* x  = (const float*)d_in[0];
  const int*   ei = (const int*)d_in[1];  // [2, E]: row then col
  const float* W1 = (const float*)d_in[2];
  const float* b1 = (const float*)d_in[3];
  const float* W2 = (const float*)d_in[4];
  const float* b2 = (const float*)d_in[5];
  float* out = (float*)d_out;

  float* ws   = (float*)d_ws;
  float* dinv = ws;                          // 100352 f
  int*  cnt   = (int*)(ws + 100352);         // 100352 i
  int*  offs  = cnt + 100352;                // 100352 i
  int*  bcur  = offs + 100352;               // 256 i
  unsigned short* Wb1 = (unsigned short*)(bcur + 256);   // 128*128 bf16
  unsigned short* Wb2 = Wb1 + 128 * 128;                 // 64*128 bf16
  int*  srow  = (int*)(Wb2 + 64 * 128);      // NB1*CAPB i (8MB)
  unsigned int* binpk = (unsigned int*)(srow + NB1 * CAPB);     // NB1*CAPB u32
  unsigned short* hd  = (unsigned short*)(binpk + NB1 * CAPB);  // NODES*128 bf16
  unsigned short* h1r = hd + (long long)NODES * 128;            // NODES*128 bf16
  unsigned short* hd2 = hd;  // reuse hd (dead after agg1)

  const int* rowi = ei;
  const int* coli = ei + EDGES;

  // ---- build: memset + [S1 | wconv] + S2 ----
  hipMemsetAsync(bcur, 0, NB1 * sizeof(int), stream);
  kS1W<<<dim3(391 + 64 + 32), dim3(256), 0, stream>>>(rowi, coli, bcur, binpk,
                                                      W1, W2, Wb1, Wb2);
  kS2<<<dim3(NB1), dim3(256), 0, stream>>>(binpk, bcur, srow, offs, cnt, dinv);

  // ---- layer 1 ----
  k_gemm1<<<dim3((NODES + 127) / 128), dim3(256), 0, stream>>>(x, Wb1, dinv, hd, NODES);
  k_agg1<<<dim3((NODES + 3) / 4), dim3(256), 0, stream>>>(hd, srow, offs, cnt, dinv, b1, h1r);

  // ---- layer 2 ----
  k_gemm2<<<dim3((NODES + 127) / 128), dim3(256), 0, stream>>>(h1r, Wb2, hd2, NODES);
  k_agg2<<<dim3((NODES + 3) / 4), dim3(256), 0, stream>>>(hd2, srow, offs, cnt, dinv, b2, out);
}

// Round 13
// 192.250 us; speedup vs baseline: 1.2790x; 1.0426x over previous
//
#include <hip/hip_runtime.h>

#define NODES 100000
#define EDGES 1600000
#define NB1 196          // col buckets: ceil(100000/512)
#define CAPB 10240       // per-bucket edge capacity (mean 8192)

typedef __attribute__((ext_vector_type(8))) short short8;
typedef __attribute__((ext_vector_type(4))) float f32x4;

// ---- bf16 helpers (RNE) -----------------------------------------------------
__device__ __forceinline__ unsigned short f2bf(float f) {
  unsigned int u = __float_as_uint(f);
  return (unsigned short)((u + 0x7fffu + ((u >> 16) & 1u)) >> 16);
}
__device__ __forceinline__ float2 up2(unsigned int u) {
  float2 f;
  f.x = __uint_as_float(u << 16);
  f.y = __uint_as_float(u & 0xffff0000u);
  return f;
}
__device__ __forceinline__ unsigned int pk2(float x, float y) {
  return ((unsigned int)f2bf(x)) | (((unsigned int)f2bf(y)) << 16);
}

// ---- pre: wconv (96 blocks) + bcur zero (1 block) ---------------------------
__global__ __launch_bounds__(256) void k_pre(const float* __restrict__ W1,
                                             const float* __restrict__ W2,
                                             unsigned short* __restrict__ Wb1,
                                             unsigned short* __restrict__ Wb2,
                                             int* __restrict__ bcur) {
  int bb = blockIdx.x;
  if (bb < 64) {
    int i = bb * 256 + threadIdx.x;        // 0..16383
    int n = i >> 7, k = i & 127;
    Wb1[i] = f2bf(W1[k * 128 + n]);
  } else if (bb < 96) {
    int i = (bb - 64) * 256 + threadIdx.x; // 0..8191
    int n = i >> 7, k = i & 127;
    Wb2[i] = f2bf(W2[k * 64 + n]);
  } else {
    if (threadIdx.x < NB1) bcur[threadIdx.x] = 0;
  }
}

// ---- S1: bin edges by col>>9; packed (row<<9)|col&511 into bucket regions ---
__global__ __launch_bounds__(256) void kS1(const int* __restrict__ rowi,
                                           const int* __restrict__ coli,
                                           int* __restrict__ bcur,
                                           unsigned int* __restrict__ binpk) {
  __shared__ int hist[NB1];
  __shared__ int base[NB1];
  const int t = threadIdx.x;
  const long long blk0 = (long long)blockIdx.x * 4096;
  for (int i = t; i < NB1; i += 256) hist[i] = 0;
  __syncthreads();
  int b[16];
  unsigned int pk[16];
#pragma unroll
  for (int q = 0; q < 4; ++q) {
    long long e = blk0 + q * 1024 + t * 4;
    if (e < EDGES) {
      int4 rv = *(const int4*)(rowi + e);
      int4 cv = *(const int4*)(coli + e);
      int rr[4] = {rv.x, rv.y, rv.z, rv.w};
      int cc[4] = {cv.x, cv.y, cv.z, cv.w};
#pragma unroll
      for (int i = 0; i < 4; ++i) {
        int idx = q * 4 + i;
        b[idx] = cc[i] >> 9;
        pk[idx] = ((unsigned int)rr[i] << 9) | (unsigned int)(cc[i] & 511);
        atomicAdd(&hist[b[idx]], 1);
      }
    } else {
#pragma unroll
      for (int i = 0; i < 4; ++i) b[q * 4 + i] = -1;
    }
  }
  __syncthreads();
  for (int i = t; i < NB1; i += 256)
    base[i] = hist[i] ? atomicAdd(&bcur[i], hist[i]) : 0;
  __syncthreads();
#pragma unroll
  for (int i = 0; i < 16; ++i) {
    if (b[i] >= 0) {
      int rel = atomicAdd(&base[b[i]], 1);
      if (rel < CAPB) binpk[b[i] * CAPB + rel] = pk[i];
    }
  }
}

// ---- S2a: per-bucket hist + scan -> offs/cnt/dinv (no scatter) --------------
__global__ __launch_bounds__(256) void kS2a(const unsigned int* __restrict__ binpk,
                                            const int* __restrict__ bcur,
                                            int* __restrict__ offs,
                                            int* __restrict__ cnt,
                                            float* __restrict__ dinv) {
  __shared__ int h[512];
  __shared__ int sc[256];
  const int k = blockIdx.x, t = threadIdx.x;
  const int beg = k * CAPB;
  const int c0 = k << 9;
  int n = bcur[k];
  if (n > CAPB) n = CAPB;
  h[t] = 0; h[t + 256] = 0;
  __syncthreads();
  for (int i = t; i < n; i += 256) atomicAdd(&h[binpk[beg + i] & 511u], 1);
  __syncthreads();
  int s0 = h[2 * t], s1 = h[2 * t + 1];
  sc[t] = s0 + s1;
  __syncthreads();
  for (int d = 1; d < 256; d <<= 1) {
    int v = (t >= d) ? sc[t - d] : 0;
    __syncthreads();
    sc[t] += v;
    __syncthreads();
  }
  int base2 = t ? sc[t - 1] : 0;
  int c = c0 + 2 * t;
  if (c < NODES) {
    offs[c] = beg + base2; cnt[c] = s0; dinv[c] = rsqrtf((float)(s0 + 1));
  }
  if (c + 1 < NODES) {
    offs[c + 1] = beg + base2 + s0; cnt[c + 1] = s1; dinv[c + 1] = rsqrtf((float)(s1 + 1));
  }
}

// ---- merged: blocks 0..195 = S2b scatter; 196..977 = gemm1 ------------------
// gemm1: HD[bf16 N][128] = bf16( (X*dinv_row) @ W1 ), B from global Wb1.
__global__ __launch_bounds__(256) void kS2bG1(const unsigned int* __restrict__ binpk,
                                              const int* __restrict__ bcur,
                                              const int* __restrict__ offs,
                                              int* __restrict__ srow,
                                              const float* __restrict__ X,
                                              const unsigned short* __restrict__ Wb,
                                              const float* __restrict__ dinv,
                                              unsigned short* __restrict__ HD) {
  __shared__ __align__(16) unsigned short As[128 * 128];  // 32KB, both roles
  const int t = threadIdx.x;

  if (blockIdx.x < NB1) {
    // -------- S2b scatter role --------
    int* cur = (int*)As;  // [512]
    const int k = blockIdx.x;
    const int beg = k * CAPB;
    const int c0 = k << 9;
    int n = bcur[k];
    if (n > CAPB) n = CAPB;
    int c = c0 + t;
    cur[t] = (c < NODES) ? offs[c] : 0;
    c += 256;
    cur[t + 256] = (c < NODES) ? offs[c] : 0;
    __syncthreads();
    for (int i = t; i < n; i += 256) {
      unsigned int p = binpk[beg + i];
      int pos = atomicAdd(&cur[p & 511u], 1);
      srow[pos] = (int)(p >> 9);
    }
    return;
  }

  // -------- gemm1 role --------
  const int r0 = (blockIdx.x - NB1) * 128;
#pragma unroll
  for (int j = 0; j < 8; ++j) {
    int u = t + j * 256;
    int row = u >> 4, slot = u & 15;
    int gr = r0 + row;
    short8 v = {0, 0, 0, 0, 0, 0, 0, 0};
    if (gr < NODES) {
      float d = dinv[gr];
      const float4* px = (const float4*)(X + (long long)gr * 128 + slot * 8);
      float4 x0 = px[0], x1 = px[1];
      unsigned short tv[8];
      tv[0] = f2bf(x0.x * d); tv[1] = f2bf(x0.y * d);
      tv[2] = f2bf(x0.z * d); tv[3] = f2bf(x0.w * d);
      tv[4] = f2bf(x1.x * d); tv[5] = f2bf(x1.y * d);
      tv[6] = f2bf(x1.z * d); tv[7] = f2bf(x1.w * d);
      v = *(short8*)tv;
    }
    *(short8*)(&As[row * 128 + ((slot ^ (row & 7)) << 3)]) = v;
  }
  __syncthreads();

  const int wid = t >> 6, l = t & 63;
  const int wm = (wid >> 1) * 64, wn = (wid & 1) * 64;
  const int lr = l & 15, lk = l >> 4;
  f32x4 acc[4][4];
#pragma unroll
  for (int mi = 0; mi < 4; ++mi)
#pragma unroll
    for (int ni = 0; ni < 4; ++ni) acc[mi][ni] = (f32x4){0.f, 0.f, 0.f, 0.f};

#pragma unroll
  for (int ks = 0; ks < 4; ++ks) {
    int slot = ks * 4 + lk;
    short8 a[4], b[4];
#pragma unroll
    for (int mi = 0; mi < 4; ++mi) {
      int row = wm + mi * 16 + lr;
      a[mi] = *(short8*)(&As[row * 128 + ((slot ^ (row & 7)) << 3)]);
    }
#pragma unroll
    for (int ni = 0; ni < 4; ++ni) {
      int row = wn + ni * 16 + lr;
      b[ni] = *(const short8*)(Wb + row * 128 + slot * 8);
    }
#pragma unroll
    for (int mi = 0; mi < 4; ++mi)
#pragma unroll
      for (int ni = 0; ni < 4; ++ni)
        acc[mi][ni] = __builtin_amdgcn_mfma_f32_16x16x32_bf16(a[mi], b[ni], acc[mi][ni], 0, 0, 0);
  }
  __syncthreads();

  const int lr4 = lk * 4;
#pragma unroll
  for (int mi = 0; mi < 4; ++mi)
#pragma unroll
    for (int ni = 0; ni < 4; ++ni)
#pragma unroll
      for (int r = 0; r < 4; ++r)
        As[(wm + mi * 16 + lr4 + r) * 128 + wn + ni * 16 + lr] = f2bf(acc[mi][ni][r]);
  __syncthreads();
#pragma unroll
  for (int j = 0; j < 8; ++j) {
    int u = t + j * 256;
    int row = u >> 4, slot = u & 15;
    int gr = r0 + row;
    if (gr < NODES)
      *(short8*)(HD + (long long)gr * 128 + slot * 8) = *(short8*)(&As[row * 128 + slot * 8]);
  }
}

// ---- CSR aggregation, F=128 (R7 inner loop, persistent grid-stride) ---------
#define AGG_BLOCKS 2048
#define AGG_WAVES (AGG_BLOCKS * 4)
__global__ __launch_bounds__(256) void k_agg1(const unsigned short* __restrict__ hd,
                                              const int* __restrict__ srow,
                                              const int* __restrict__ offs,
                                              const int* __restrict__ cnt,
                                              const float* __restrict__ dinv,
                                              const float* __restrict__ b1,
                                              unsigned short* __restrict__ h1r) {
  const int wid = (blockIdx.x << 2) + (threadIdx.x >> 6);
  const int lane = threadIdx.x & 63;
  const unsigned int* H = (const unsigned int*)hd;
  const float2 b = ((const float2*)b1)[lane];
  for (int w = wid; w < NODES; w += AGG_WAVES) {
    float2 a0 = up2(H[(long long)w * 64 + lane]);  // self-loop
    float2 a1 = {0.f, 0.f}, a2 = {0.f, 0.f}, a3 = {0.f, 0.f};
    float2 a4 = {0.f, 0.f}, a5 = {0.f, 0.f}, a6 = {0.f, 0.f}, a7 = {0.f, 0.f};
    int off = offs[w], n = cnt[w];
    int j = 0;
    for (; j + 7 < n; j += 8) {
      int r0 = srow[off + j],     r1 = srow[off + j + 1];
      int r2 = srow[off + j + 2], r3 = srow[off + j + 3];
      int r4 = srow[off + j + 4], r5 = srow[off + j + 5];
      int r6 = srow[off + j + 6], r7 = srow[off + j + 7];
      float2 v0 = up2(H[(long long)r0 * 64 + lane]);
      float2 v1 = up2(H[(long long)r1 * 64 + lane]);
      float2 v2 = up2(H[(long long)r2 * 64 + lane]);
      float2 v3 = up2(H[(long long)r3 * 64 + lane]);
      float2 v4 = up2(H[(long long)r4 * 64 + lane]);
      float2 v5 = up2(H[(long long)r5 * 64 + lane]);
      float2 v6 = up2(H[(long long)r6 * 64 + lane]);
      float2 v7 = up2(H[(long long)r7 * 64 + lane]);
      a0.x += v0.x; a0.y += v0.y; a1.x += v1.x; a1.y += v1.y;
      a2.x += v2.x; a2.y += v2.y; a3.x += v3.x; a3.y += v3.y;
      a4.x += v4.x; a4.y += v4.y; a5.x += v5.x; a5.y += v5.y;
      a6.x += v6.x; a6.y += v6.y; a7.x += v7.x; a7.y += v7.y;
    }
    for (; j + 3 < n; j += 4) {
      int r0 = srow[off + j],     r1 = srow[off + j + 1];
      int r2 = srow[off + j + 2], r3 = srow[off + j + 3];
      float2 v0 = up2(H[(long long)r0 * 64 + lane]);
      float2 v1 = up2(H[(long long)r1 * 64 + lane]);
      float2 v2 = up2(H[(long long)r2 * 64 + lane]);
      float2 v3 = up2(H[(long long)r3 * 64 + lane]);
      a0.x += v0.x; a0.y += v0.y; a1.x += v1.x; a1.y += v1.y;
      a2.x += v2.x; a2.y += v2.y; a3.x += v3.x; a3.y += v3.y;
    }
    for (; j < n; ++j) {
      float2 v = up2(H[(long long)srow[off + j] * 64 + lane]);
      a0.x += v.x; a0.y += v.y;
    }
    float ax = ((a0.x + a1.x) + (a2.x + a3.x)) + ((a4.x + a5.x) + (a6.x + a7.x));
    float ay = ((a0.y + a1.y) + (a2.y + a3.y)) + ((a4.y + a5.y) + (a6.y + a7.y));
    float dc = dinv[w];
    float ox = fmaxf(fmaf(ax, dc, b.x), 0.f) * dc;  // pre-scaled for layer-2
    float oy = fmaxf(fmaf(ay, dc, b.y), 0.f) * dc;
    ((unsigned int*)h1r)[(long long)w * 64 + lane] = pk2(ox, oy);
  }
}

// ---- MFMA GEMM layer2: HD2[bf16] = bf16( h1r @ W2 ), B from global ----------
__global__ __launch_bounds__(256) void k_gemm2(const unsigned short* __restrict__ H1,
                                               const unsigned short* __restrict__ Wb,
                                               unsigned short* __restrict__ HD2,
                                               int nrows) {
  __shared__ unsigned short As[128 * 128];
  const int t = threadIdx.x;
  const int r0 = blockIdx.x * 128;

#pragma unroll
  for (int j = 0; j < 8; ++j) {
    int u = t + j * 256;
    int row = u >> 4, slot = u & 15;
    int gr = r0 + row;
    short8 v = {0, 0, 0, 0, 0, 0, 0, 0};
    if (gr < nrows) v = *(const short8*)(H1 + (long long)gr * 128 + slot * 8);
    *(short8*)(&As[row * 128 + ((slot ^ (row & 7)) << 3)]) = v;
  }
  __syncthreads();

  const int wid = t >> 6, l = t & 63;
  const int wm = wid * 32;
  const int lr = l & 15, lk = l >> 4;
  f32x4 acc[2][4];
#pragma unroll
  for (int mi = 0; mi < 2; ++mi)
#pragma unroll
    for (int ni = 0; ni < 4; ++ni) acc[mi][ni] = (f32x4){0.f, 0.f, 0.f, 0.f};

#pragma unroll
  for (int ks = 0; ks < 4; ++ks) {
    int slot = ks * 4 + lk;
    short8 a[2], b[4];
#pragma unroll
    for (int mi = 0; mi < 2; ++mi) {
      int row = wm + mi * 16 + lr;
      a[mi] = *(short8*)(&As[row * 128 + ((slot ^ (row & 7)) << 3)]);
    }
#pragma unroll
    for (int ni = 0; ni < 4; ++ni) {
      int row = ni * 16 + lr;
      b[ni] = *(const short8*)(Wb + row * 128 + slot * 8);
    }
#pragma unroll
    for (int mi = 0; mi < 2; ++mi)
#pragma unroll
      for (int ni = 0; ni < 4; ++ni)
        acc[mi][ni] = __builtin_amdgcn_mfma_f32_16x16x32_bf16(a[mi], b[ni], acc[mi][ni], 0, 0, 0);
  }
  __syncthreads();

  const int lr4 = lk * 4;
#pragma unroll
  for (int mi = 0; mi < 2; ++mi)
#pragma unroll
    for (int ni = 0; ni < 4; ++ni)
#pragma unroll
      for (int r = 0; r < 4; ++r)
        As[(wm + mi * 16 + lr4 + r) * 64 + ni * 16 + lr] = f2bf(acc[mi][ni][r]);
  __syncthreads();
#pragma unroll
  for (int j = 0; j < 4; ++j) {
    int u = t + j * 256;
    int row = u >> 3, slot = u & 7;
    int gr = r0 + row;
    if (gr < nrows)
      *(short8*)(HD2 + (long long)gr * 64 + slot * 8) = *(short8*)(&As[row * 64 + slot * 8]);
  }
}

// ---- CSR aggregation, F=64: quarter-wave (R12 proven), grid-stride ----------
__global__ __launch_bounds__(256) void k_agg2(const unsigned short* __restrict__ hd2,
                                              const int* __restrict__ srow,
                                              const int* __restrict__ offs,
                                              const int* __restrict__ cnt,
                                              const float* __restrict__ dinv,
                                              const float* __restrict__ b2,
                                              float* __restrict__ outp) {
  const int wid = (blockIdx.x << 2) + (threadIdx.x >> 6);
  const int lane = threadIdx.x & 63;
  const int fq = lane & 15;   // feature quad
  const int eq = lane >> 4;   // edge quarter
  const unsigned int f8 = (unsigned int)fq << 3;
  const char* H = (const char*)hd2;  // rows are 128B
  const float4 b = ((const float4*)b2)[fq];

  for (int w = wid; w < NODES; w += AGG_WAVES) {
    float4 a0 = {0.f, 0.f, 0.f, 0.f}, a1 = a0, a2 = a0, a3 = a0;
    if (eq == 0) {  // self-loop
      uint2 u = *(const uint2*)(H + (((unsigned int)w) << 7) + f8);
      float2 lo = up2(u.x), hi = up2(u.y);
      a0.x = lo.x; a0.y = lo.y; a0.z = hi.x; a0.w = hi.y;
    }
    int off = offs[w], n = cnt[w];
    const int* sp = srow + off;
    int j = 0;
    for (; j + 16 <= n; j += 16) {
      unsigned int o0 = (((unsigned int)sp[j + eq])      << 7) + f8;
      unsigned int o1 = (((unsigned int)sp[j + 4 + eq])  << 7) + f8;
      unsigned int o2 = (((unsigned int)sp[j + 8 + eq])  << 7) + f8;
      unsigned int o3 = (((unsigned int)sp[j + 12 + eq]) << 7) + f8;
      uint2 u0 = *(const uint2*)(H + o0);
      uint2 u1 = *(const uint2*)(H + o1);
      uint2 u2 = *(const uint2*)(H + o2);
      uint2 u3 = *(const uint2*)(H + o3);
      float2 l0 = up2(u0.x), h0 = up2(u0.y);
      float2 l1 = up2(u1.x), h1 = up2(u1.y);
      float2 l2 = up2(u2.x), h2 = up2(u2.y);
      float2 l3 = up2(u3.x), h3 = up2(u3.y);
      a0.x += l0.x; a0.y += l0.y; a0.z += h0.x; a0.w += h0.y;
      a1.x += l1.x; a1.y += l1.y; a1.z += h1.x; a1.w += h1.y;
      a2.x += l2.x; a2.y += l2.y; a2.z += h2.x; a2.w += h2.y;
      a3.x += l3.x; a3.y += l3.y; a3.z += h3.x; a3.w += h3.y;
    }
    int rem = n - j;
    if (rem >= 4) {
      uint2 u = *(const uint2*)(H + ((((unsigned int)sp[j + eq]) << 7) + f8));
      float2 lo = up2(u.x), hi = up2(u.y);
      a0.x += lo.x; a0.y += lo.y; a0.z += hi.x; a0.w += hi.y;
    }
    if (rem >= 8) {
      uint2 u = *(const uint2*)(H + ((((unsigned int)sp[j + 4 + eq]) << 7) + f8));
      float2 lo = up2(u.x), hi = up2(u.y);
      a1.x += lo.x; a1.y += lo.y; a1.z += hi.x; a1.w += hi.y;
    }
    if (rem >= 12) {
      uint2 u = *(const uint2*)(H + ((((unsigned int)sp[j + 8 + eq]) << 7) + f8));
      float2 lo = up2(u.x), hi = up2(u.y);
      a2.x += lo.x; a2.y += lo.y; a2.z += hi.x; a2.w += hi.y;
    }
    int last = j + (rem & ~3);
    if (eq < (rem & 3)) {
      uint2 u = *(const uint2*)(H + ((((unsigned int)sp[last + eq]) << 7) + f8));
      float2 lo = up2(u.x), hi = up2(u.y);
      a3.x += lo.x; a3.y += lo.y; a3.z += hi.x; a3.w += hi.y;
    }
    float4 s;
    s.x = (a0.x + a1.x) + (a2.x + a3.x);
    s.y = (a0.y + a1.y) + (a2.y + a3.y);
    s.z = (a0.z + a1.z) + (a2.z + a3.z);
    s.w = (a0.w + a1.w) + (a2.w + a3.w);
    s.x += __shfl_xor(s.x, 16); s.y += __shfl_xor(s.y, 16);
    s.z += __shfl_xor(s.z, 16); s.w += __shfl_xor(s.w, 16);
    s.x += __shfl_xor(s.x, 32); s.y += __shfl_xor(s.y, 32);
    s.z += __shfl_xor(s.z, 32); s.w += __shfl_xor(s.w, 32);
    if (eq == 0) {
      float dc = dinv[w];
      float4 o;
      o.x = fmaf(s.x, dc, b.x);
      o.y = fmaf(s.y, dc, b.y);
      o.z = fmaf(s.z, dc, b.z);
      o.w = fmaf(s.w, dc, b.w);
      ((float4*)outp)[(long long)w * 16 + fq] = o;
    }
  }
}

extern "C" void kernel_launch(void* const* d_in, const int* in_sizes, int n_in,
                              void* d_out, int out_size, void* d_ws, size_t ws_size,
                              hipStream_t stream) {
  const float* x  = (const float*)d_in[0];
  const int*   ei = (const int*)d_in[1];  // [2, E]: row then col
  const float* W1 = (const float*)d_in[2];
  const float* b1 = (const float*)d_in[3];
  const float* W2 = (const float*)d_in[4];
  const float* b2 = (const float*)d_in[5];
  float* out = (float*)d_out;

  float* ws   = (float*)d_ws;
  float* dinv = ws;                          // 100352 f
  int*  cnt   = (int*)(ws + 100352);         // 100352 i
  int*  offs  = cnt + 100352;                // 100352 i
  int*  bcur  = offs + 100352;               // 256 i
  unsigned short* Wb1 = (unsigned short*)(bcur + 256);   // 128*128 bf16
  unsigned short* Wb2 = Wb1 + 128 * 128;                 // 64*128 bf16
  int*  srow  = (int*)(Wb2 + 64 * 128);      // NB1*CAPB i (8MB)
  unsigned int* binpk = (unsigned int*)(srow + NB1 * CAPB);     // NB1*CAPB u32
  unsigned short* hd  = (unsigned short*)(binpk + NB1 * CAPB);  // NODES*128 bf16
  unsigned short* h1r = hd + (long long)NODES * 128;            // NODES*128 bf16
  unsigned short* hd2 = hd;  // reuse hd (dead after agg1)

  const int* rowi = ei;
  const int* coli = ei + EDGES;

  // ---- build (scatter overlapped with gemm1) ----
  k_pre<<<dim3(97), dim3(256), 0, stream>>>(W1, W2, Wb1, Wb2, bcur);
  kS1<<<dim3((EDGES + 4095) / 4096), dim3(256), 0, stream>>>(rowi, coli, bcur, binpk);
  kS2a<<<dim3(NB1), dim3(256), 0, stream>>>(binpk, bcur, offs, cnt, dinv);
  kS2bG1<<<dim3(NB1 + 782), dim3(256), 0, stream>>>(binpk, bcur, offs, srow,
                                                    x, Wb1, dinv, hd);

  // ---- layer 1 aggregation ----
  k_agg1<<<dim3(AGG_BLOCKS), dim3(256), 0, stream>>>(hd, srow, offs, cnt, dinv, b1, h1r);

  // ---- layer 2 ----
  k_gemm2<<<dim3((NODES + 127) / 128), dim3(256), 0, stream>>>(h1r, Wb2, hd2, NODES);
  k_agg2<<<dim3(AGG_BLOCKS), dim3(256), 0, stream>>>(hd2, srow, offs, cnt, dinv, b2, out);
}